// Round 10
// baseline (570.391 us; speedup 1.0000x reference)
//
#include <hip/hip_runtime.h>

#define D 128
#define BN_EPS 1e-5f
#define K_ELL 40
#define NB_AGG 1024
#define NB_FILL 1024

typedef __attribute__((ext_vector_type(8))) short bf16x8;
typedef __attribute__((ext_vector_type(4))) float f32x4;

__device__ __forceinline__ unsigned bf16rne(float f) {
    unsigned u = __float_as_uint(f);
    return (u + 0x7fffu + ((u >> 16) & 1u)) >> 16;
}
__device__ __forceinline__ float bflo(unsigned p) { return __uint_as_float(p << 16); }
__device__ __forceinline__ float bfhi(unsigned p) { return __uint_as_float(p & 0xffff0000u); }

// ============ fused: gemm (blocks < gemm_nb) + degree/ELL fill (rest) ============
__global__ __launch_bounds__(256) void gemm_fill(
    const float* __restrict__ x, const float* __restrict__ W,
    const int* __restrict__ prow, const int* __restrict__ pcol,
    int* __restrict__ deg, int* __restrict__ ell,
    int2* __restrict__ ovf, int* __restrict__ ovf_cnt,
    ushort* __restrict__ hb, int n, int E, int gemm_nb)
{
    __shared__ ushort xsb[64][136];   // [row][k], pad -> free 2-way banks
    __shared__ ushort wsb[128][136];  // [col][k]
    int tid = threadIdx.x;

    if (blockIdx.x >= gemm_nb) {
        // ---- fill role: one-pass degree count + ELL ----
        int gtid = (blockIdx.x - gemm_nb) * 256 + tid;
        for (int e = gtid; e < E; e += NB_FILL * 256) {
            int c = pcol[e];
            int r = prow[e];
            int p = atomicAdd(&deg[c], 1);
            if (p < K_ELL) {
                ell[c * K_ELL + p] = r;
            } else {  // statistically never at deg~Poisson(10)
                int q = atomicAdd(ovf_cnt, 1);
                ovf[q] = make_int2(c, r);
            }
        }
        return;
    }

    // ---- gemm role: h = bf16(x) @ bf16(W) via MFMA, bf16 store ----
    int wave = tid >> 6;
    int lane = tid & 63;
    int row0 = blockIdx.x * 64;

    // stage W fp32 -> bf16 transposed [c][k] (W is 64KB, L2-resident)
    #pragma unroll
    for (int i = 0; i < 16; i++) {
        int flat = i * 256 + tid;   // 0..4095
        int k = flat >> 5;          // 0..127
        int c4 = flat & 31;
        float4 v = *(const float4*)&W[k * D + c4 * 4];
        wsb[c4 * 4 + 0][k] = (ushort)bf16rne(v.x);
        wsb[c4 * 4 + 1][k] = (ushort)bf16rne(v.y);
        wsb[c4 * 4 + 2][k] = (ushort)bf16rne(v.z);
        wsb[c4 * 4 + 3][k] = (ushort)bf16rne(v.w);
    }
    // stage x tile fp32 -> bf16
    {
        int r = tid >> 2, kq = tid & 3;
        int grow = row0 + r;
        if (grow >= n) grow = n - 1;
        const float4* src = (const float4*)&x[(size_t)grow * D + kq * 32];
        uint* dst = (uint*)&xsb[r][kq * 32];
        #pragma unroll
        for (int q = 0; q < 8; q++) {
            float4 v = src[q];
            dst[q * 2]     = bf16rne(v.x) | (bf16rne(v.y) << 16);
            dst[q * 2 + 1] = bf16rne(v.z) | (bf16rne(v.w) << 16);
        }
    }
    __syncthreads();

    f32x4 acc[4][2];
    #pragma unroll
    for (int mt = 0; mt < 4; mt++)
        #pragma unroll
        for (int nt = 0; nt < 2; nt++)
            acc[mt][nt] = (f32x4){0.f, 0.f, 0.f, 0.f};

    int ar = lane & 15;
    int ako = (lane >> 4) * 8;
    #pragma unroll
    for (int k0 = 0; k0 < 128; k0 += 32) {
        bf16x8 a[4], b[2];
        #pragma unroll
        for (int mt = 0; mt < 4; mt++)
            a[mt] = *(const bf16x8*)&xsb[mt * 16 + ar][k0 + ako];
        #pragma unroll
        for (int nt = 0; nt < 2; nt++)
            b[nt] = *(const bf16x8*)&wsb[wave * 32 + nt * 16 + ar][k0 + ako];
        #pragma unroll
        for (int mt = 0; mt < 4; mt++)
            #pragma unroll
            for (int nt = 0; nt < 2; nt++)
                acc[mt][nt] = __builtin_amdgcn_mfma_f32_16x16x32_bf16(
                    a[mt], b[nt], acc[mt][nt], 0, 0, 0);
    }

    int col = lane & 15, rq = (lane >> 4) * 4;
    #pragma unroll
    for (int mt = 0; mt < 4; mt++) {
        #pragma unroll
        for (int r = 0; r < 4; r++) {
            int grow = row0 + mt * 16 + rq + r;
            if (grow < n) {
                #pragma unroll
                for (int nt = 0; nt < 2; nt++)
                    hb[(size_t)grow * D + wave * 32 + nt * 16 + col] =
                        (ushort)bf16rne(acc[mt][nt][r]);
            }
        }
    }
}

// ============ aggregate: 2 nodes/wave full-row interleave + last-block BN fold ============
__global__ __launch_bounds__(512) void aggregate(
    const unsigned* __restrict__ hb, const int* __restrict__ deg,
    const int* __restrict__ ell, const int2* __restrict__ ovf,
    const int* __restrict__ ovf_cnt, const float* __restrict__ bias,
    const float* __restrict__ gamma, const float* __restrict__ beta,
    float* __restrict__ out, float* __restrict__ partials,
    int* __restrict__ ticket, float* __restrict__ scs_g, float* __restrict__ shs_g,
    int n, float invN)
{
    int tid = threadIdx.x;
    int wave = tid >> 6;      // 0..7
    int lane = tid & 63;
    int half = lane >> 5;     // preload owner: 0 -> nodeA, 1 -> nodeB
    int sub = lane & 31;
    float2 bv = *(const float2*)&bias[lane * 2];
    float s1a = 0.f, s1b = 0.f, s2a = 0.f, s2b = 0.f;

    for (int base = blockIdx.x * 16 + wave * 2; base < n; base += gridDim.x * 16) {
        int n0 = base;
        bool has1 = (base + 1 < n);
        int n1 = has1 ? base + 1 : base;
        int c0T = deg[n0];
        int c1T = deg[n1];
        float dc0 = rsqrtf((float)c0T + 1.0f);
        float dc1 = rsqrtf((float)c1T + 1.0f);
        unsigned hp0 = hb[(size_t)n0 * 64 + lane];
        unsigned hp1 = hb[(size_t)n1 * 64 + lane];
        float ax0 = dc0 * bflo(hp0), ay0 = dc0 * bfhi(hp0);
        float ax1 = dc1 * bflo(hp1), ay1 = dc1 * bfhi(hp1);
        int c0E = c0T < 32 ? c0T : 32;
        int c1E = c1T < 32 ? c1T : 32;
        if (!has1) c1E = 0;
        // lane preload: half 0 holds node0 slots 0..31, half 1 holds node1 slots
        int mynode = half ? n1 : n0;
        int mycE = half ? c1E : c0E;
        int es = (sub < mycE) ? ell[mynode * K_ELL + sub] : mynode;  // pad -> self
        float ed = (sub < mycE) ? rsqrtf((float)deg[es] + 1.0f) : 0.f;
        int cap = c0E > c1E ? c0E : c1E;
        int iters = (cap + 3) >> 2;
        for (int it = 0; it < iters; it++) {
            int e = it * 4;
            int sa0 = __shfl(es, e),      sb0 = __shfl(es, e + 1);
            int sc0i = __shfl(es, e + 2), sd0 = __shfl(es, e + 3);
            int sa1 = __shfl(es, 32 + e),     sb1 = __shfl(es, 33 + e);
            int sc1i = __shfl(es, 34 + e),    sd1 = __shfl(es, 35 + e);
            float da0 = __shfl(ed, e),      db0 = __shfl(ed, e + 1);
            float dc0w = __shfl(ed, e + 2), dd0 = __shfl(ed, e + 3);
            float da1 = __shfl(ed, 32 + e),     db1 = __shfl(ed, 33 + e);
            float dc1w = __shfl(ed, 34 + e),    dd1 = __shfl(ed, 35 + e);
            unsigned ha0 = hb[(size_t)sa0 * 64 + lane];
            unsigned hb0 = hb[(size_t)sb0 * 64 + lane];
            unsigned hc0 = hb[(size_t)sc0i * 64 + lane];
            unsigned hd0 = hb[(size_t)sd0 * 64 + lane];
            unsigned ha1 = hb[(size_t)sa1 * 64 + lane];
            unsigned hb1 = hb[(size_t)sb1 * 64 + lane];
            unsigned hc1 = hb[(size_t)sc1i * 64 + lane];
            unsigned hd1 = hb[(size_t)sd1 * 64 + lane];
            ax0 += da0 * bflo(ha0);  ay0 += da0 * bfhi(ha0);
            ax0 += db0 * bflo(hb0);  ay0 += db0 * bfhi(hb0);
            ax0 += dc0w * bflo(hc0); ay0 += dc0w * bfhi(hc0);
            ax0 += dd0 * bflo(hd0);  ay0 += dd0 * bfhi(hd0);
            ax1 += da1 * bflo(ha1);  ay1 += da1 * bfhi(ha1);
            ax1 += db1 * bflo(hb1);  ay1 += db1 * bfhi(hb1);
            ax1 += dc1w * bflo(hc1); ay1 += dc1w * bfhi(hc1);
            ax1 += dd1 * bflo(hd1);  ay1 += dd1 * bfhi(hd1);
        }
        // rare tails: ELL slots 32..K_ELL, then overflow list
        for (int e = 32; e < c0T && e < K_ELL; e++) {
            int s = ell[n0 * K_ELL + e];
            float dv = rsqrtf((float)deg[s] + 1.0f);
            unsigned hq = hb[(size_t)s * 64 + lane];
            ax0 += dv * bflo(hq); ay0 += dv * bfhi(hq);
        }
        if (has1) for (int e = 32; e < c1T && e < K_ELL; e++) {
            int s = ell[n1 * K_ELL + e];
            float dv = rsqrtf((float)deg[s] + 1.0f);
            unsigned hq = hb[(size_t)s * 64 + lane];
            ax1 += dv * bflo(hq); ay1 += dv * bfhi(hq);
        }
        if (c0T > K_ELL || (has1 && c1T > K_ELL)) {
            int novf = *ovf_cnt;
            for (int j = 0; j < novf; j++) {
                int2 q = ovf[j];
                float dv = rsqrtf((float)deg[q.y] + 1.0f);
                unsigned hq = hb[(size_t)q.y * 64 + lane];
                if (q.x == n0) { ax0 += dv * bflo(hq); ay0 += dv * bfhi(hq); }
                if (has1 && q.x == n1) { ax1 += dv * bflo(hq); ay1 += dv * bfhi(hq); }
            }
        }
        float ox0 = dc0 * ax0 + bv.x;
        float oy0 = dc0 * ay0 + bv.y;
        *(float2*)&out[(size_t)n0 * D + lane * 2] = make_float2(ox0, oy0);
        s1a += ox0; s1b += oy0; s2a += ox0 * ox0; s2b += oy0 * oy0;
        if (has1) {
            float ox1 = dc1 * ax1 + bv.x;
            float oy1 = dc1 * ay1 + bv.y;
            *(float2*)&out[(size_t)n1 * D + lane * 2] = make_float2(ox1, oy1);
            s1a += ox1; s1b += oy1; s2a += ox1 * ox1; s2b += oy1 * oy1;
        }
    }

    // per-block partial reduce -> partials[block][256]
    __shared__ float l1[8][128], l2[8][128];
    __shared__ float stats[256];
    __shared__ int amlast;
    l1[wave][lane * 2] = s1a; l1[wave][lane * 2 + 1] = s1b;
    l2[wave][lane * 2] = s2a; l2[wave][lane * 2 + 1] = s2b;
    __syncthreads();
    if (tid < 256) {
        int col = tid & 127;
        float v;
        if (tid < 128) {
            v = l1[0][col] + l1[1][col] + l1[2][col] + l1[3][col] +
                l1[4][col] + l1[5][col] + l1[6][col] + l1[7][col];
        } else {
            v = l2[0][col] + l2[1][col] + l2[2][col] + l2[3][col] +
                l2[4][col] + l2[5][col] + l2[6][col] + l2[7][col];
        }
        partials[(size_t)blockIdx.x * 256 + tid] = v;
    }
    __threadfence();
    __syncthreads();
    if (tid == 0) amlast = (atomicAdd(ticket, 1) == (int)gridDim.x - 1);
    __syncthreads();
    if (amlast) {
        __threadfence();  // acquire other blocks' partials
        if (tid < 256) {
            float s = 0.f;
            for (int r = 0; r < (int)gridDim.x; r++)
                s += partials[(size_t)r * 256 + tid];
            stats[tid] = s;
        }
        __syncthreads();
        if (tid < 128) {
            float m = stats[tid] * invN;
            float var = stats[tid + 128] * invN - m * m;
            float sc = rsqrtf(var + BN_EPS) * gamma[tid];
            scs_g[tid] = sc;
            shs_g[tid] = beta[tid] - m * sc;
        }
    }
}

// ============ BN apply + ReLU (in place, float4) ============
__global__ __launch_bounds__(256) void bn_finalize(float4* __restrict__ out4,
                                                   const float* __restrict__ scs,
                                                   const float* __restrict__ shs,
                                                   int total4) {
    int i0 = blockIdx.x * 256 + threadIdx.x;
    int c = (i0 * 4) & 127;  // grid stride in floats is a multiple of 128
    float4 sc = *(const float4*)&scs[c];
    float4 sh = *(const float4*)&shs[c];
    for (int i = i0; i < total4; i += gridDim.x * 256) {
        float4 v = out4[i];
        v.x = fmaxf(fmaf(v.x, sc.x, sh.x), 0.f);
        v.y = fmaxf(fmaf(v.y, sc.y, sh.y), 0.f);
        v.z = fmaxf(fmaf(v.z, sc.z, sh.z), 0.f);
        v.w = fmaxf(fmaf(v.w, sc.w, sh.w), 0.f);
        out4[i] = v;
    }
}

extern "C" void kernel_launch(void* const* d_in, const int* in_sizes, int n_in,
                              void* d_out, int out_size, void* d_ws, size_t ws_size,
                              hipStream_t stream) {
    const float* x     = (const float*)d_in[0];
    const int*   pos   = (const int*)d_in[1];
    const float* W     = (const float*)d_in[3];
    const float* bias  = (const float*)d_in[4];
    const float* gamma = (const float*)d_in[5];
    const float* beta  = (const float*)d_in[6];
    float* out = (float*)d_out;

    int N  = in_sizes[0] / D;
    int EP = in_sizes[1] / 2;
    const int* prow = pos;
    const int* pcol = pos + EP;
    int gemm_nb = (N + 63) / 64;

    auto align = [](size_t v) { return (v + 255) & ~(size_t)255; };
    char* p = (char*)d_ws;
    // ---- zeroed region (one memset): deg, ovf_cnt, ticket ----
    int*    deg     = (int*)p;    p += align((size_t)N * 4);
    int*    ovf_cnt = (int*)p;    p += align(256);
    int*    ticket  = (int*)p;    p += align(256);
    size_t zbytes = (size_t)(p - (char*)d_ws);
    // ---- rest ----
    int*    ell      = (int*)p;    p += align((size_t)N * K_ELL * 4);
    int2*   ovf      = (int2*)p;   p += align((size_t)EP * 8);
    ushort* hb       = (ushort*)p; p += align((size_t)N * D * 2);
    float*  partials = (float*)p;  p += align((size_t)NB_AGG * 256 * 4);
    float*  scs      = (float*)p;  p += align((size_t)D * 4);
    float*  shs      = (float*)p;  p += align((size_t)D * 4);

    hipMemsetAsync(d_ws, 0, zbytes, stream);
    gemm_fill<<<gemm_nb + NB_FILL, 256, 0, stream>>>(x, W, prow, pcol, deg, ell, ovf,
                                                     ovf_cnt, hb, N, EP, gemm_nb);
    aggregate<<<NB_AGG, 512, 0, stream>>>((const unsigned*)hb, deg, ell, ovf, ovf_cnt,
                                          bias, gamma, beta, out, partials, ticket,
                                          scs, shs, N, 1.0f / (float)N);
    bn_finalize<<<1600, 256, 0, stream>>>((float4*)out, scs, shs, N * D / 4);
}

// Round 11
// 164.088 us; speedup vs baseline: 3.4761x; 3.4761x over previous
//
#include <hip/hip_runtime.h>

#define D 128
#define BN_EPS 1e-5f
#define K_ELL 40
#define NB_AGG 1024
#define NB_FILL 1024

typedef __attribute__((ext_vector_type(8))) short bf16x8;
typedef __attribute__((ext_vector_type(4))) float f32x4;

__device__ __forceinline__ unsigned bf16rne(float f) {
    unsigned u = __float_as_uint(f);
    return (u + 0x7fffu + ((u >> 16) & 1u)) >> 16;
}
__device__ __forceinline__ float bflo(unsigned p) { return __uint_as_float(p << 16); }
__device__ __forceinline__ float bfhi(unsigned p) { return __uint_as_float(p & 0xffff0000u); }

// ============ fused: gemm (blocks < gemm_nb) + degree/ELL fill (rest) ============
__global__ __launch_bounds__(256) void gemm_fill(
    const float* __restrict__ x, const float* __restrict__ W,
    const int* __restrict__ prow, const int* __restrict__ pcol,
    int* __restrict__ deg, int* __restrict__ ell,
    int2* __restrict__ ovf, int* __restrict__ ovf_cnt,
    ushort* __restrict__ hb, int n, int E, int gemm_nb)
{
    __shared__ ushort xsb[64][136];   // [row][k], pad -> free 2-way banks
    __shared__ ushort wsb[128][136];  // [col][k]
    int tid = threadIdx.x;

    if (blockIdx.x >= gemm_nb) {
        // ---- fill role: one-pass degree count + ELL ----
        int gtid = (blockIdx.x - gemm_nb) * 256 + tid;
        for (int e = gtid; e < E; e += NB_FILL * 256) {
            int c = pcol[e];
            int r = prow[e];
            int p = atomicAdd(&deg[c], 1);
            if (p < K_ELL) {
                ell[c * K_ELL + p] = r;
            } else {  // statistically never at deg~Poisson(10)
                int q = atomicAdd(ovf_cnt, 1);
                ovf[q] = make_int2(c, r);
            }
        }
        return;
    }

    // ---- gemm role: h = bf16(x) @ bf16(W) via MFMA, bf16 store ----
    int wave = tid >> 6;
    int lane = tid & 63;
    int row0 = blockIdx.x * 64;

    // stage W fp32 -> bf16 transposed [c][k] (W is 64KB, L2-resident)
    #pragma unroll
    for (int i = 0; i < 16; i++) {
        int flat = i * 256 + tid;   // 0..4095
        int k = flat >> 5;          // 0..127
        int c4 = flat & 31;
        float4 v = *(const float4*)&W[k * D + c4 * 4];
        wsb[c4 * 4 + 0][k] = (ushort)bf16rne(v.x);
        wsb[c4 * 4 + 1][k] = (ushort)bf16rne(v.y);
        wsb[c4 * 4 + 2][k] = (ushort)bf16rne(v.z);
        wsb[c4 * 4 + 3][k] = (ushort)bf16rne(v.w);
    }
    // stage x tile fp32 -> bf16
    {
        int r = tid >> 2, kq = tid & 3;
        int grow = row0 + r;
        if (grow >= n) grow = n - 1;
        const float4* src = (const float4*)&x[(size_t)grow * D + kq * 32];
        uint* dst = (uint*)&xsb[r][kq * 32];
        #pragma unroll
        for (int q = 0; q < 8; q++) {
            float4 v = src[q];
            dst[q * 2]     = bf16rne(v.x) | (bf16rne(v.y) << 16);
            dst[q * 2 + 1] = bf16rne(v.z) | (bf16rne(v.w) << 16);
        }
    }
    __syncthreads();

    f32x4 acc[4][2];
    #pragma unroll
    for (int mt = 0; mt < 4; mt++)
        #pragma unroll
        for (int nt = 0; nt < 2; nt++)
            acc[mt][nt] = (f32x4){0.f, 0.f, 0.f, 0.f};

    int ar = lane & 15;
    int ako = (lane >> 4) * 8;
    #pragma unroll
    for (int k0 = 0; k0 < 128; k0 += 32) {
        bf16x8 a[4], b[2];
        #pragma unroll
        for (int mt = 0; mt < 4; mt++)
            a[mt] = *(const bf16x8*)&xsb[mt * 16 + ar][k0 + ako];
        #pragma unroll
        for (int nt = 0; nt < 2; nt++)
            b[nt] = *(const bf16x8*)&wsb[wave * 32 + nt * 16 + ar][k0 + ako];
        #pragma unroll
        for (int mt = 0; mt < 4; mt++)
            #pragma unroll
            for (int nt = 0; nt < 2; nt++)
                acc[mt][nt] = __builtin_amdgcn_mfma_f32_16x16x32_bf16(
                    a[mt], b[nt], acc[mt][nt], 0, 0, 0);
    }

    int col = lane & 15, rq = (lane >> 4) * 4;
    #pragma unroll
    for (int mt = 0; mt < 4; mt++) {
        #pragma unroll
        for (int r = 0; r < 4; r++) {
            int grow = row0 + mt * 16 + rq + r;
            if (grow < n) {
                #pragma unroll
                for (int nt = 0; nt < 2; nt++)
                    hb[(size_t)grow * D + wave * 32 + nt * 16 + col] =
                        (ushort)bf16rne(acc[mt][nt][r]);
            }
        }
    }
}

// ---------------- aggregation: wave/node, ELL gather, unroll-4, partials out ----------------
__global__ __launch_bounds__(512) void aggregate(const unsigned* __restrict__ hb,
                                                 const int* __restrict__ deg,
                                                 const int* __restrict__ ell,
                                                 const int2* __restrict__ ovf,
                                                 const int* __restrict__ ovf_cnt,
                                                 const float* __restrict__ bias,
                                                 float* __restrict__ out,
                                                 float* __restrict__ partials, int n) {
    int tid = threadIdx.x;
    int wave = tid >> 6;      // 0..7
    int lane = tid & 63;
    float2 bv = *(const float2*)&bias[lane * 2];
    float s1a = 0.f, s1b = 0.f, s2a = 0.f, s2b = 0.f;

    for (int node = blockIdx.x * 8 + wave; node < n; node += gridDim.x * 8) {
        int cntT = deg[node];
        float dc = rsqrtf((float)cntT + 1.0f);
        int cntE = cntT < K_ELL ? cntT : K_ELL;
        unsigned hp = hb[(size_t)node * 64 + lane];
        float ax = dc * bflo(hp), ay = dc * bfhi(hp);
        int es = (lane < cntE) ? ell[node * K_ELL + lane] : 0;
        float ed = (lane < cntE) ? rsqrtf((float)deg[es] + 1.0f) : 0.f;
        int e = 0;
        for (; e + 4 <= cntE; e += 4) {
            int sA = __shfl(es, e), sB = __shfl(es, e + 1);
            int sC = __shfl(es, e + 2), sD = __shfl(es, e + 3);
            float dA = __shfl(ed, e), dB = __shfl(ed, e + 1);
            float dC = __shfl(ed, e + 2), dD = __shfl(ed, e + 3);
            unsigned hA = hb[(size_t)sA * 64 + lane];
            unsigned hB = hb[(size_t)sB * 64 + lane];
            unsigned hC = hb[(size_t)sC * 64 + lane];
            unsigned hD = hb[(size_t)sD * 64 + lane];
            ax += dA * bflo(hA); ay += dA * bfhi(hA);
            ax += dB * bflo(hB); ay += dB * bfhi(hB);
            ax += dC * bflo(hC); ay += dC * bfhi(hC);
            ax += dD * bflo(hD); ay += dD * bfhi(hD);
        }
        for (; e < cntE; e++) {
            int s = __shfl(es, e);
            float dv = __shfl(ed, e);
            unsigned hq = hb[(size_t)s * 64 + lane];
            ax += dv * bflo(hq); ay += dv * bfhi(hq);
        }
        if (cntT > K_ELL) {  // overflow scan (practically never taken)
            int novf = *ovf_cnt;
            for (int j = 0; j < novf; j++) {
                int2 q = ovf[j];
                if (q.x == node) {
                    float dv = rsqrtf((float)deg[q.y] + 1.0f);
                    unsigned hq = hb[(size_t)q.y * 64 + lane];
                    ax += dv * bflo(hq); ay += dv * bfhi(hq);
                }
            }
        }
        float ox = dc * ax + bv.x;
        float oy = dc * ay + bv.y;
        *(float2*)&out[(size_t)node * D + lane * 2] = make_float2(ox, oy);
        s1a += ox; s1b += oy;
        s2a += ox * ox; s2b += oy * oy;
    }

    // 8-wave LDS reduce, one coalesced 1 KB partial write per block (no atomics)
    __shared__ float l1[8][128], l2[8][128];
    l1[wave][lane * 2] = s1a; l1[wave][lane * 2 + 1] = s1b;
    l2[wave][lane * 2] = s2a; l2[wave][lane * 2 + 1] = s2b;
    __syncthreads();
    if (tid < 256) {
        int col = tid & 127;
        float v;
        if (tid < 128) {
            v = l1[0][col] + l1[1][col] + l1[2][col] + l1[3][col] +
                l1[4][col] + l1[5][col] + l1[6][col] + l1[7][col];
        } else {
            v = l2[0][col] + l2[1][col] + l2[2][col] + l2[3][col] +
                l2[4][col] + l2[5][col] + l2[6][col] + l2[7][col];
        }
        partials[(size_t)blockIdx.x * 256 + tid] = v;
    }
}

// ---------------- fold partials [NB_AGG][256] into gsum/gsumsq (parallel) ----------------
__global__ __launch_bounds__(256) void bn_reduce(const float* __restrict__ partials,
                                                 float* __restrict__ gsum,
                                                 float* __restrict__ gsumsq, int nrows) {
    int tid = threadIdx.x;
    float s = 0.f;
    for (int r = blockIdx.x; r < nrows; r += gridDim.x)
        s += partials[(size_t)r * 256 + tid];
    if (tid < 128) atomicAdd(&gsum[tid], s);
    else           atomicAdd(&gsumsq[tid - 128], s);
}

// ---------------- BN finalize + ReLU (in place, float4) ----------------
__global__ __launch_bounds__(256) void bn_finalize(float4* __restrict__ out4,
                                                   const float* __restrict__ gsum,
                                                   const float* __restrict__ gsumsq,
                                                   const float* __restrict__ gamma,
                                                   const float* __restrict__ beta,
                                                   int total4, float invN) {
    int i0 = blockIdx.x * 256 + threadIdx.x;
    int c = (i0 * 4) & 127;  // grid stride in floats is a multiple of 128
    float4 g4 = *(const float4*)&gsum[c];
    float4 q4 = *(const float4*)&gsumsq[c];
    float4 gm = *(const float4*)&gamma[c];
    float4 bt = *(const float4*)&beta[c];
    float m0 = g4.x * invN, m1 = g4.y * invN, m2 = g4.z * invN, m3 = g4.w * invN;
    float sc0 = rsqrtf(q4.x * invN - m0 * m0 + BN_EPS) * gm.x;
    float sc1 = rsqrtf(q4.y * invN - m1 * m1 + BN_EPS) * gm.y;
    float sc2 = rsqrtf(q4.z * invN - m2 * m2 + BN_EPS) * gm.z;
    float sc3 = rsqrtf(q4.w * invN - m3 * m3 + BN_EPS) * gm.w;
    float sh0 = bt.x - m0 * sc0, sh1 = bt.y - m1 * sc1;
    float sh2 = bt.z - m2 * sc2, sh3 = bt.w - m3 * sc3;
    for (int i = i0; i < total4; i += gridDim.x * 256) {
        float4 v = out4[i];
        v.x = fmaxf(fmaf(v.x, sc0, sh0), 0.f);
        v.y = fmaxf(fmaf(v.y, sc1, sh1), 0.f);
        v.z = fmaxf(fmaf(v.z, sc2, sh2), 0.f);
        v.w = fmaxf(fmaf(v.w, sc3, sh3), 0.f);
        out4[i] = v;
    }
}

extern "C" void kernel_launch(void* const* d_in, const int* in_sizes, int n_in,
                              void* d_out, int out_size, void* d_ws, size_t ws_size,
                              hipStream_t stream) {
    const float* x     = (const float*)d_in[0];
    const int*   pos   = (const int*)d_in[1];
    const float* W     = (const float*)d_in[3];
    const float* bias  = (const float*)d_in[4];
    const float* gamma = (const float*)d_in[5];
    const float* beta  = (const float*)d_in[6];
    float* out = (float*)d_out;

    int N  = in_sizes[0] / D;
    int EP = in_sizes[1] / 2;
    const int* prow = pos;
    const int* pcol = pos + EP;
    int gemm_nb = (N + 63) / 64;

    auto align = [](size_t v) { return (v + 255) & ~(size_t)255; };
    char* p = (char*)d_ws;
    // ---- zeroed region (one memset): deg, ovf_cnt, gsum, gsumsq ----
    int*    deg     = (int*)p;    p += align((size_t)N * 4);
    int*    ovf_cnt = (int*)p;    p += align(256);
    float*  gsum    = (float*)p;  p += align((size_t)D * 4);
    float*  gsumsq  = (float*)p;  p += align((size_t)D * 4);
    size_t zbytes = (size_t)(p - (char*)d_ws);
    // ---- rest ----
    int*    ell      = (int*)p;    p += align((size_t)N * K_ELL * 4);
    int2*   ovf      = (int2*)p;   p += align((size_t)EP * 8);
    ushort* hb       = (ushort*)p; p += align((size_t)N * D * 2);
    float*  partials = (float*)p;  p += align((size_t)NB_AGG * 256 * 4);

    hipMemsetAsync(d_ws, 0, zbytes, stream);
    gemm_fill<<<gemm_nb + NB_FILL, 256, 0, stream>>>(x, W, prow, pcol, deg, ell, ovf,
                                                     ovf_cnt, hb, N, EP, gemm_nb);
    aggregate<<<NB_AGG, 512, 0, stream>>>((const unsigned*)hb, deg, ell, ovf, ovf_cnt,
                                          bias, out, partials, N);
    bn_reduce<<<64, 256, 0, stream>>>(partials, gsum, gsumsq, NB_AGG);
    bn_finalize<<<1600, 256, 0, stream>>>((float4*)out, gsum, gsumsq, gamma, beta,
                                          N * D / 4, 1.0f / (float)N);
}